// Round 2
// baseline (13788.426 us; speedup 1.0000x reference)
//
#include <hip/hip_runtime.h>
#include <stdint.h>

// ODE-LSTM (PersonActivityModel): B=256,T=128,IN=64,H=512,C=11, fp32 in/out.
//
// u-space RK4 folding: M = W2^T W1^T, d = b2·W1^T:
//   u1 = h·W1^T+b1; D_i = tanh(u_i)·M; u2=u1+.5dt(D1+d); u3=u1+.5dt(D2+d);
//   u4=u1+dt(D3+d); SM=D1+2D2+2D3+D4; u_next=u1+(dt/6)SM+dt·d;
//   S=t1+2t2+2t3+t4 accumulated over 3 unfolds; h += (dt/6)(S_tot·W2^T)+3dt·b2.
// Output folded: out = h·(Wc·Wo)^T + (Wc·bo + bc), one deferred GEMM.
// Gates folded:  z = [h|x]·[Whh|Wih]^T + (bih+bhh), K=576.
//
// Decomposition: 16 independent clusters (16 batches each), ONE 512-thread WG
// (8 waves) per cluster => all exchange in LDS, no cross-WG sync at all.
// 14 dependent matmul phases/timestep, fp16 MFMA 16x16x32, fp32 accum/state.

#define H_  512
#define B_  256
#define T_  128
#define IN_ 64
#define NC_ 11
#define GB_ 16
#define LD_ 520   // LDS row stride (+8 fp16 pad: breaks ds_read_b128 bank conflicts)

typedef _Float16 h8v __attribute__((ext_vector_type(8)));
typedef float    f4v __attribute__((ext_vector_type(4)));

__device__ __forceinline__ float fsigm(float x) { return 1.0f / (1.0f + __expf(-x)); }
__device__ __forceinline__ float ftanh(float x) { return 1.0f - 2.0f / (1.0f + __expf(2.0f * x)); }

// ---------------- prep kernels (fp32 weights -> fp16 MFMA B-fragment tables) ----------------

// Mtmp[m][n] = sum_k W2[k][m] * W1[n][k]   (fp32)  [M = W2^T W1^T]
__global__ void prep_M(const float* __restrict__ W1, const float* __restrict__ W2,
                       float* __restrict__ Mtmp) {
  __shared__ float w1s[8][512];
  int tid = threadIdx.x;
  int n0 = blockIdx.x * 8;
  for (int i = tid; i < 8 * 512; i += 256) {
    int nn = i >> 9, m = i & 511;
    w1s[nn][m] = W1[(n0 + nn) * 512 + m];
  }
  __syncthreads();
  float acc0[8] = {0,0,0,0,0,0,0,0}, acc1[8] = {0,0,0,0,0,0,0,0};
  for (int m = 0; m < 512; ++m) {
    float a = W2[m * 512 + tid];
    float b = W2[m * 512 + 256 + tid];
#pragma unroll
    for (int j = 0; j < 8; ++j) { acc0[j] += a * w1s[j][m]; acc1[j] += b * w1s[j][m]; }
  }
  for (int j = 0; j < 8; ++j) {
    Mtmp[(size_t)tid * 512 + n0 + j]         = acc0[j];
    Mtmp[(size_t)(tid + 256) * 512 + n0 + j] = acc1[j];
  }
}

// dvec[n] = sum_m b2[m]W1[n][m]; bprime[c] = bc[c]+sum Wc[c][m]bo[m];
// Wco[c][h] = sum_m Wc[c][m]Wo[m][h]
__global__ void prep_small(const float* __restrict__ W1, const float* __restrict__ b2,
                           const float* __restrict__ Wc, const float* __restrict__ Wo,
                           const float* __restrict__ bo, const float* __restrict__ bc,
                           float* __restrict__ dvec, float* __restrict__ Wco,
                           float* __restrict__ bprime) {
  __shared__ float wcs[NC_ * 512];
  int tid = threadIdx.x;
  if (blockIdx.x == 0) {
    for (int n = tid; n < 512; n += 256) {
      float acc = 0.f;
      for (int m = 0; m < 512; ++m) acc += b2[m] * W1[n * 512 + m];
      dvec[n] = acc;
    }
  } else if (blockIdx.x == 1) {
    if (tid < NC_) {
      float acc = bc[tid];
      for (int m = 0; m < 512; ++m) acc += Wc[tid * 512 + m] * bo[m];
      bprime[tid] = acc;
    }
  } else {
    for (int i = tid; i < NC_ * 512; i += 256) wcs[i] = Wc[i];
    __syncthreads();
    int h = (blockIdx.x - 2) * 256 + tid;
    float acc[NC_];
#pragma unroll
    for (int c = 0; c < NC_; ++c) acc[c] = 0.f;
    for (int m = 0; m < 512; ++m) {
      float wo = Wo[m * 512 + h];
#pragma unroll
      for (int c = 0; c < NC_; ++c) acc[c] += wo * wcs[c * 512 + m];
    }
    for (int c = 0; c < NC_; ++c) Wco[c * 512 + h] = acc[c];
  }
}

// B-fragment tables (fp16): frag-block fb = 64 lanes x 8 halfs (1KB).
// B[k][n]: lane holds n = tile*16+(lane&15), k = kc*32 + ((lane>>4)&3)*8 + j.
// Gates table: fb = (g*32 + tile)*18 + kc, n_global = g*512 + tile*16 + lm,
// k<512 -> Whh, k>=512 -> Wih (K=576).
__global__ void prep_wtilde(const float* __restrict__ Whh, const float* __restrict__ Wih,
                            _Float16* __restrict__ Wtil) {
  int gidx = blockIdx.x * 256 + threadIdx.x;  // 2304 fb * 64 lanes
  int lane = gidx & 63, fb = gidx >> 6;
  int kc = fb % 18; int t2 = fb / 18;
  int t = t2 & 31, g = t2 >> 5;
  int n = g * 512 + t * 16 + (lane & 15);
  int k = kc * 32 + ((lane >> 4) & 3) * 8;
  _Float16 vals[8];
  if (k < 512) {
#pragma unroll
    for (int j = 0; j < 8; ++j) vals[j] = (_Float16)Whh[(size_t)n * 512 + k + j];
  } else {
#pragma unroll
    for (int j = 0; j < 8; ++j) vals[j] = (_Float16)Wih[(size_t)n * 64 + (k - 512) + j];
  }
  *(h8v*)(Wtil + (size_t)fb * 512 + lane * 8) = *(h8v*)vals;
}

// W table (512x512): fb = tile*16 + kc;  B[k][n] = W[n][k]
__global__ void prep_fragW(const float* __restrict__ W, _Float16* __restrict__ dst) {
  int gidx = blockIdx.x * 256 + threadIdx.x;  // 512 fb * 64 lanes
  int lane = gidx & 63, fb = gidx >> 6;
  int t = fb >> 4, kc = fb & 15;
  int n = t * 16 + (lane & 15);
  int k = kc * 32 + ((lane >> 4) & 3) * 8;
  _Float16 vals[8];
#pragma unroll
  for (int j = 0; j < 8; ++j) vals[j] = (_Float16)W[(size_t)n * 512 + k + j];
  *(h8v*)(dst + (size_t)fb * 512 + lane * 8) = *(h8v*)vals;
}

// M table: B[k][n] = Mtmp[k][n]
__global__ void prep_fragM(const float* __restrict__ Mtmp, _Float16* __restrict__ dst) {
  int gidx = blockIdx.x * 256 + threadIdx.x;
  int lane = gidx & 63, fb = gidx >> 6;
  int t = fb >> 4, kc = fb & 15;
  int n = t * 16 + (lane & 15);
  int k = kc * 32 + ((lane >> 4) & 3) * 8;
  _Float16 vals[8];
#pragma unroll
  for (int j = 0; j < 8; ++j) vals[j] = (_Float16)Mtmp[(size_t)(k + j) * 512 + n];
  *(h8v*)(dst + (size_t)fb * 512 + lane * 8) = *(h8v*)vals;
}

// ---------------- recurrence: one WG (512 thr, 8 waves) per 16-batch cluster ----------------

// One 16x512 @ 512x512 phase: wave w computes col-tiles 4w..4w+3.
// A: LDS [16][LD_] fp16 row-major (batch-major). Result D[tt] row=quad*4+r, col=(4w+tt)*16+lm.
__device__ __forceinline__ void mm4(const _Float16* __restrict__ ACT,
                                    const _Float16* __restrict__ Btab,
                                    int w, int lane, int lm, int quad, f4v D[4]) {
  f4v a0 = {0,0,0,0}, a1 = {0,0,0,0}, a2 = {0,0,0,0}, a3 = {0,0,0,0};
  const _Float16* arow = ACT + lm * LD_ + quad * 8;
  const h8v* bt = (const h8v*)Btab;
#pragma unroll 4
  for (int kc = 0; kc < 16; ++kc) {
    h8v a = *(const h8v*)(arow + kc * 32);
    size_t base = (size_t)((4 * w) * 16 + kc) * 64 + lane;
    a0 = __builtin_amdgcn_mfma_f32_16x16x32_f16(a, bt[base],            a0, 0, 0, 0);
    a1 = __builtin_amdgcn_mfma_f32_16x16x32_f16(a, bt[base + 16 * 64],  a1, 0, 0, 0);
    a2 = __builtin_amdgcn_mfma_f32_16x16x32_f16(a, bt[base + 32 * 64],  a2, 0, 0, 0);
    a3 = __builtin_amdgcn_mfma_f32_16x16x32_f16(a, bt[base + 48 * 64],  a3, 0, 0, 0);
  }
  D[0] = a0; D[1] = a1; D[2] = a2; D[3] = a3;
}

__launch_bounds__(512, 1)
__global__ void recur(const float* __restrict__ x,
                      const float* __restrict__ tin,
                      const float* __restrict__ bih,
                      const float* __restrict__ bhh,
                      const float* __restrict__ b1g,
                      const float* __restrict__ b2g,
                      const _Float16* __restrict__ Wtil,
                      const _Float16* __restrict__ W1T,
                      const _Float16* __restrict__ W2T,
                      const _Float16* __restrict__ MF,
                      const float* __restrict__ dvec,
                      _Float16* __restrict__ Hsave) {
  const int cl = blockIdx.x;
  const int tid = threadIdx.x, w = tid >> 6, lane = tid & 63;
  const int lm = lane & 15, quad = lane >> 4;

  __shared__ __align__(16) _Float16 ACT[16 * LD_];
  __shared__ float zbs[4 * 512];

  // init: zero activations (h0=0), stage gate biases
  for (int i = tid; i < 16 * LD_; i += 512) ACT[i] = (_Float16)0.f;
  for (int i = tid; i < 2048; i += 512) zbs[i] = bih[i] + bhh[i];

  int cg[4];
#pragma unroll
  for (int tt = 0; tt < 4; ++tt) cg[tt] = (4 * w + tt) * 16 + lm;
  float b1r[4], dvr[4], b2r[4];
#pragma unroll
  for (int tt = 0; tt < 4; ++tt) { b1r[tt] = b1g[cg[tt]]; dvr[tt] = dvec[cg[tt]]; b2r[tt] = b2g[cg[tt]]; }

  float c_[4][4] = {{0}}, h_[4][4] = {{0}};
  float u1a[4][4], SSa[4][4], SMa[4][4];
  f4v D[4];
  __syncthreads();

  for (int ts = 0; ts < T_; ++ts) {
    float dt_[4];
#pragma unroll
    for (int r = 0; r < 4; ++r)
      dt_[r] = tin[(cl * GB_ + quad * 4 + r) * T_ + ts] * (1.0f / 3.0f);

    // ---- P1: z = [h|x]·Wtil^T (K=576, N=2048) ----
    {
      f4v z[4][4];
#pragma unroll
      for (int g = 0; g < 4; ++g)
#pragma unroll
        for (int tt = 0; tt < 4; ++tt) z[g][tt] = (f4v){0, 0, 0, 0};
      const _Float16* arow = ACT + lm * LD_ + quad * 8;
      const float* xrow = x + ((size_t)(cl * GB_ + lm) * T_ + ts) * IN_ + quad * 8;
      const h8v* wt = (const h8v*)Wtil;
      for (int kc = 0; kc < 18; ++kc) {
        h8v a;
        if (kc < 16) {
          a = *(const h8v*)(arow + kc * 32);
        } else {
          const float* xp = xrow + (kc - 16) * 32;
          float4 f0 = *(const float4*)xp;
          float4 f1 = *(const float4*)(xp + 4);
          a[0] = (_Float16)f0.x; a[1] = (_Float16)f0.y; a[2] = (_Float16)f0.z; a[3] = (_Float16)f0.w;
          a[4] = (_Float16)f1.x; a[5] = (_Float16)f1.y; a[6] = (_Float16)f1.z; a[7] = (_Float16)f1.w;
        }
#pragma unroll
        for (int g = 0; g < 4; ++g) {
#pragma unroll
          for (int tt = 0; tt < 4; ++tt) {
            size_t idx = (size_t)((g * 32 + 4 * w + tt) * 18 + kc) * 64 + lane;
            z[g][tt] = __builtin_amdgcn_mfma_f32_16x16x32_f16(a, wt[idx], z[g][tt], 0, 0, 0);
          }
        }
      }
      __syncthreads();
#pragma unroll
      for (int tt = 0; tt < 4; ++tt) {
#pragma unroll
        for (int r = 0; r < 4; ++r) {
          float zi = z[0][tt][r] + zbs[0 * 512 + cg[tt]];
          float zf = z[1][tt][r] + zbs[1 * 512 + cg[tt]];
          float zg = z[2][tt][r] + zbs[2 * 512 + cg[tt]];
          float zo = z[3][tt][r] + zbs[3 * 512 + cg[tt]];
          float cv = fsigm(zf) * c_[tt][r] + fsigm(zi) * ftanh(zg);
          c_[tt][r] = cv;
          float hv = fsigm(zo) * ftanh(cv);
          h_[tt][r] = hv;
          ACT[(quad * 4 + r) * LD_ + cg[tt]] = (_Float16)hv;
        }
      }
    }
    __syncthreads();

    // ---- P2: u1 = h·W1^T + b1 ----
    mm4(ACT, W1T, w, lane, lm, quad, D);
    __syncthreads();
#pragma unroll
    for (int tt = 0; tt < 4; ++tt)
#pragma unroll
      for (int r = 0; r < 4; ++r) {
        float uv = D[tt][r] + b1r[tt];
        u1a[tt][r] = uv;
        float t1v = ftanh(uv);
        SSa[tt][r] = t1v;
        ACT[(quad * 4 + r) * LD_ + cg[tt]] = (_Float16)t1v;
      }
    __syncthreads();

    // ---- 3 RK4 unfolds in u-space ----
#pragma unroll 1
    for (int uf = 0; uf < 3; ++uf) {
      // s1: D1 = t1·M
      mm4(ACT, MF, w, lane, lm, quad, D);
      __syncthreads();
#pragma unroll
      for (int tt = 0; tt < 4; ++tt)
#pragma unroll
        for (int r = 0; r < 4; ++r) {
          float Dv = D[tt][r];
          float u2 = u1a[tt][r] + 0.5f * dt_[r] * (Dv + dvr[tt]);
          SMa[tt][r] = Dv;
          float t2v = ftanh(u2);
          SSa[tt][r] += 2.0f * t2v;
          ACT[(quad * 4 + r) * LD_ + cg[tt]] = (_Float16)t2v;
        }
      __syncthreads();

      // s2: D2 = t2·M
      mm4(ACT, MF, w, lane, lm, quad, D);
      __syncthreads();
#pragma unroll
      for (int tt = 0; tt < 4; ++tt)
#pragma unroll
        for (int r = 0; r < 4; ++r) {
          float Dv = D[tt][r];
          float u3 = u1a[tt][r] + 0.5f * dt_[r] * (Dv + dvr[tt]);
          SMa[tt][r] += 2.0f * Dv;
          float t3v = ftanh(u3);
          SSa[tt][r] += 2.0f * t3v;
          ACT[(quad * 4 + r) * LD_ + cg[tt]] = (_Float16)t3v;
        }
      __syncthreads();

      // s3: D3 = t3·M
      mm4(ACT, MF, w, lane, lm, quad, D);
      __syncthreads();
#pragma unroll
      for (int tt = 0; tt < 4; ++tt)
#pragma unroll
        for (int r = 0; r < 4; ++r) {
          float Dv = D[tt][r];
          float u4 = u1a[tt][r] + dt_[r] * (Dv + dvr[tt]);
          SMa[tt][r] += 2.0f * Dv;
          float t4v = ftanh(u4);
          SSa[tt][r] += t4v;
          ACT[(quad * 4 + r) * LD_ + cg[tt]] = (uf < 2) ? (_Float16)t4v : (_Float16)SSa[tt][r];
        }
      __syncthreads();

      if (uf < 2) {
        // s4: D4 = t4·M ; u_next = u1 + (dt/6)SM + dt·d ; t1' = tanh(u_next)
        mm4(ACT, MF, w, lane, lm, quad, D);
        __syncthreads();
#pragma unroll
        for (int tt = 0; tt < 4; ++tt)
#pragma unroll
          for (int r = 0; r < 4; ++r) {
            float Dv = D[tt][r];
            SMa[tt][r] += Dv;
            float un = u1a[tt][r] + (dt_[r] * (1.0f / 6.0f)) * SMa[tt][r] + dt_[r] * dvr[tt];
            u1a[tt][r] = un;
            float t1v = ftanh(un);
            SSa[tt][r] += t1v;
            ACT[(quad * 4 + r) * LD_ + cg[tt]] = (_Float16)t1v;
          }
        __syncthreads();
      }
    }

    // ---- P_h: h += (dt/6)·(S_tot·W2^T) + 3dt·b2 ; publish h ----
    mm4(ACT, W2T, w, lane, lm, quad, D);
    __syncthreads();
#pragma unroll
    for (int tt = 0; tt < 4; ++tt)
#pragma unroll
      for (int r = 0; r < 4; ++r) {
        h_[tt][r] += (dt_[r] * (1.0f / 6.0f)) * D[tt][r] + (3.0f * dt_[r]) * b2r[tt];
        ACT[(quad * 4 + r) * LD_ + cg[tt]] = (_Float16)h_[tt][r];
      }
    __syncthreads();

    // vectorized ACT -> Hsave[ts+1] (read-only wrt ACT; next P1 also only reads)
    for (int u = tid; u < 1024; u += 512) {
      int row = u >> 6, seg = u & 63;
      *(h8v*)(Hsave + ((size_t)(ts + 1) * B_ + cl * GB_ + row) * H_ + seg * 8) =
          *(const h8v*)(ACT + row * LD_ + seg * 8);
    }
  }
}

// ---------------- final projection: out = h·Wco^T + bprime (fp32 out) ----------------
__global__ void final_out(const _Float16* __restrict__ Hsave,
                          const float* __restrict__ Wco,
                          const float* __restrict__ bprime,
                          float* __restrict__ out) {
  __shared__ float wcs[NC_][520];
  int tid = threadIdx.x;
  for (int i = tid; i < NC_ * 512; i += 256) wcs[i >> 9][i & 511] = Wco[i];
  __syncthreads();
  int r0 = blockIdx.x * 64;
  int rl = tid >> 4, cc = tid & 15;
  for (int pass = 0; pass < 4; ++pass) {
    int row = r0 + pass * 16 + rl;        // row = b*T + t
    int b = row >> 7, t = row & 127;
    const _Float16* hrow = Hsave + ((size_t)(t + 1) * B_ + b) * H_;
    if (cc < NC_) {
      float acc = 0.f;
      for (int k8 = 0; k8 < 64; ++k8) {
        h8v hv = *(const h8v*)(hrow + k8 * 8);
#pragma unroll
        for (int j = 0; j < 8; ++j) acc += (float)hv[j] * wcs[cc][k8 * 8 + j];
      }
      out[(size_t)row * NC_ + cc] = acc + bprime[cc];
    }
  }
}

extern "C" void kernel_launch(void* const* d_in, const int* in_sizes, int n_in,
                              void* d_out, int out_size, void* d_ws, size_t ws_size,
                              hipStream_t stream) {
  (void)in_sizes; (void)n_in; (void)out_size; (void)ws_size;
  const float* x   = (const float*)d_in[0];
  const float* tin = (const float*)d_in[1];
  const float* Wih = (const float*)d_in[2];
  const float* Whh = (const float*)d_in[3];
  const float* bih = (const float*)d_in[4];
  const float* bhh = (const float*)d_in[5];
  const float* W1  = (const float*)d_in[6];
  const float* b1  = (const float*)d_in[7];
  const float* W2  = (const float*)d_in[8];
  const float* b2  = (const float*)d_in[9];
  const float* Wo  = (const float*)d_in[10];
  const float* bo  = (const float*)d_in[11];
  const float* Wc  = (const float*)d_in[12];
  const float* bc  = (const float*)d_in[13];

  char* ws = (char*)d_ws;
  size_t off = 0;
  auto alloc = [&](size_t bytes) -> void* {
    void* p = ws + off;
    off = (off + bytes + 1023) & ~(size_t)1023;
    return p;
  };
  _Float16* Wtil  = (_Float16*)alloc((size_t)2304 * 512 * 2);  // gates B-table (K=576)
  _Float16* W1T   = (_Float16*)alloc((size_t)512 * 512 * 2);
  _Float16* W2T   = (_Float16*)alloc((size_t)512 * 512 * 2);
  _Float16* MF    = (_Float16*)alloc((size_t)512 * 512 * 2);
  float*    Mtmp  = (float*)alloc((size_t)512 * 512 * 4);
  float*    dvec  = (float*)alloc(512 * 4);
  float*    WcoF  = (float*)alloc((size_t)NC_ * 512 * 4);
  float*    bprim = (float*)alloc(64);
  _Float16* Hsave = (_Float16*)alloc((size_t)(T_ + 1) * B_ * H_ * 2);

  prep_M<<<64, 256, 0, stream>>>(W1, W2, Mtmp);
  prep_small<<<4, 256, 0, stream>>>(W1, b2, Wc, Wo, bo, bc, dvec, WcoF, bprim);
  prep_wtilde<<<576, 256, 0, stream>>>(Whh, Wih, Wtil);
  prep_fragW<<<128, 256, 0, stream>>>(W1, W1T);
  prep_fragW<<<128, 256, 0, stream>>>(W2, W2T);
  prep_fragM<<<128, 256, 0, stream>>>(Mtmp, MF);
  recur<<<16, 512, 0, stream>>>(x, tin, bih, bhh, b1, b2, Wtil, W1T, W2T, MF,
                                dvec, Hsave);
  final_out<<<512, 256, 0, stream>>>(Hsave, WcoF, bprim, (float*)d_out);
}